// Round 16
// baseline (1590.672 us; speedup 1.0000x reference)
//
#include <hip/hip_runtime.h>
#include <float.h>
#include <math.h>

#define EPSF 1e-5f
#define NRM_BIAS 2048.0f

constexpr int B_  = 8;
constexpr int CIN = 512;
constexpr int T_  = 4096;
constexpr int K_  = 8;
constexpr int N_  = 2048;
constexpr int D_  = 256;
constexpr int BT  = B_ * T_;          // 32768 tokens

typedef _Float16 v8h __attribute__((ext_vector_type(8)));
typedef _Float16 v4h __attribute__((ext_vector_type(4)));
typedef float    v4f __attribute__((ext_vector_type(4)));

static __device__ __forceinline__ unsigned umn(unsigned a, unsigned b) { return a < b ? a : b; }
static __device__ __forceinline__ unsigned umx(unsigned a, unsigned b) { return a > b ? a : b; }

// ---------------------------------------------------------------------------
// prep: inv = 1/clamp(u), nrm = sum_d e^2 + NRM_BIAS; f16 codebook in
// MFMA-fragment-swizzled order (proven, unchanged).
// ---------------------------------------------------------------------------
__global__ void __launch_bounds__(256) prep_kernel(const float* __restrict__ embed_sum,
                                                   const float* __restrict__ usage,
                                                   float* __restrict__ inv,
                                                   float* __restrict__ nrm,
                                                   _Float16* __restrict__ ehs) {
  int w    = threadIdx.x >> 6;
  int lane = threadIdx.x & 63;
  int kn   = blockIdx.x * 4 + w;
  int k    = kn >> 11, n = kn & (N_ - 1);
  const float* s = embed_sum + (size_t)kn * D_;
  float um = fmaxf(usage[kn], EPSF);
  float4 sv = *(const float4*)(s + lane * 4);
  float e0 = sv.x / um, e1 = sv.y / um, e2 = sv.z / um, e3 = sv.w / um;
  float v = e0 * e0 + e1 * e1 + e2 * e2 + e3 * e3;

  int half = n >> 10, chunk = (n >> 4) & 63, r = n & 15;
  int cg = lane >> 1, sub = lane & 1;
  v4h h4; h4[0] = (_Float16)e0; h4[1] = (_Float16)e1;
  h4[2] = (_Float16)e2; h4[3] = (_Float16)e3;
  size_t off16 = ((size_t)((k * 2 + half) * 64 + chunk)) * 4096
               + (size_t)(cg * 16 + r) * 8 + (size_t)sub * 4;
  *(v4h*)(ehs + off16) = h4;

  for (int off = 32; off > 0; off >>= 1) v += __shfl_down(v, off);
  if (lane == 0) { inv[kn] = 1.0f / um; nrm[kn] = v + NRM_BIAS; }
}

// ---------------------------------------------------------------------------
// wprep_x / wc / wprep_o (proven, unchanged)
// ---------------------------------------------------------------------------
__global__ void __launch_bounds__(64) wprep_x_kernel(const float* __restrict__ w_in,
                                                     v8h* __restrict__ afragX) {
  int lane = threadIdx.x;
  int mt = blockIdx.x >> 4, kstep = blockIdx.x & 15;
  int m = mt * 16 + (lane & 15), k0 = kstep * 32 + (lane >> 4) * 8;
  const float* src = w_in + (size_t)m * CIN + k0;
  float4 f0 = *(const float4*)src, f1 = *(const float4*)(src + 4);
  float e[8] = {f0.x, f0.y, f0.z, f0.w, f1.x, f1.y, f1.z, f1.w};
  v8h h, l;
#pragma unroll
  for (int j = 0; j < 8; j++) {
    _Float16 hh = (_Float16)e[j];
    h[j] = hh; l[j] = (_Float16)(e[j] - (float)hh);
  }
  v8h* dst = afragX + ((size_t)blockIdx.x * 64 + lane) * 2;
  dst[0] = h; dst[1] = l;
}

__global__ void __launch_bounds__(256) wc_kernel(const float* __restrict__ w_out,
                                                 const float* __restrict__ w_in,
                                                 float* __restrict__ wc) {
  int c  = blockIdx.x >> 1;
  int cp = (blockIdx.x & 1) * 256 + threadIdx.x;
  float acc = 0.f;
  for (int d = 0; d < D_; d++)
    acc += w_out[(size_t)c * D_ + d] * w_in[(size_t)d * CIN + cp];
  wc[(size_t)c * CIN + cp] = acc;
}

__global__ void __launch_bounds__(64) wprep_o_kernel(const float* __restrict__ wc,
                                                     const float* __restrict__ w_out,
                                                     v8h* __restrict__ afragO) {
  int lane = threadIdx.x;
  int mt = blockIdx.x / 24, kstep = blockIdx.x % 24;
  int m = mt * 16 + (lane & 15), k0 = kstep * 32 + (lane >> 4) * 8;
  float e[8];
  if (k0 < CIN) {
    const float* s = wc + (size_t)m * CIN + k0;
#pragma unroll
    for (int j = 0; j < 8; j++) e[j] = s[j];
  } else {
    const float* s = w_out + (size_t)m * D_ + (k0 - CIN);
#pragma unroll
    for (int j = 0; j < 8; j++) e[j] = -s[j];
  }
  v8h h, l;
#pragma unroll
  for (int j = 0; j < 8; j++) {
    _Float16 hh = (_Float16)e[j];
    h[j] = hh; l[j] = (_Float16)(e[j] - (float)hh);
  }
  v8h* dst = afragO + ((size_t)blockIdx.x * 64 + lane) * 2;
  dst[0] = h; dst[1] = l;
}

// ---------------------------------------------------------------------------
// proj_x: split-3 f16 MFMA, m-split x2 (proven round-6 kernel, unchanged)
// ---------------------------------------------------------------------------
__global__ void __launch_bounds__(256, 4) proj_x_kernel(const float* __restrict__ emb,
                                                        const v8h* __restrict__ afragX,
                                                        float* __restrict__ rb) {
  int tid = threadIdx.x, wave = tid >> 6, lane = tid & 63;
  int lr = lane & 15, lg = lane >> 4;
  int tb = blockIdx.x >> 1, nb = blockIdx.x & 1;
  int t0 = tb * 64 + wave * 16;
  int b  = t0 >> 12;
  const float* ebase = emb + (size_t)b * CIN * T_ + (t0 & (T_ - 1)) + lr;

  v4f acc[8];
#pragma unroll
  for (int nt = 0; nt < 8; nt++) acc[nt] = (v4f){0.f, 0.f, 0.f, 0.f};

  for (int ks = 0; ks < 16; ks++) {
    float e[8];
#pragma unroll
    for (int j = 0; j < 8; j++)
      e[j] = ebase[(size_t)(ks * 32 + lg * 8 + j) * T_];
    v8h Eh, El;
#pragma unroll
    for (int j = 0; j < 8; j++) {
      _Float16 hh = (_Float16)e[j];
      Eh[j] = hh; El[j] = (_Float16)(e[j] - (float)hh);
    }
    const v8h* ap = afragX + ((size_t)ks * 64 + lane) * 2;
#pragma unroll
    for (int nt = 0; nt < 8; nt++) {
      int mt = nb * 8 + nt;
      v8h Wh = ap[(size_t)mt * 2048];
      v8h Wl = ap[(size_t)mt * 2048 + 1];
      acc[nt] = __builtin_amdgcn_mfma_f32_16x16x32_f16(Eh, Wh, acc[nt], 0, 0, 0);
      acc[nt] = __builtin_amdgcn_mfma_f32_16x16x32_f16(El, Wh, acc[nt], 0, 0, 0);
      acc[nt] = __builtin_amdgcn_mfma_f32_16x16x32_f16(Eh, Wl, acc[nt], 0, 0, 0);
    }
  }
#pragma unroll
  for (int nt = 0; nt < 8; nt++)
#pragma unroll
    for (int r = 0; r < 4; r++)
      rb[(size_t)(t0 + lg * 4 + r) * D_ + (nb * 8 + nt) * 16 + lr] = acc[nt][r];
}

// ---------------------------------------------------------------------------
// proj_out (proven round-5 kernel, unchanged)
// ---------------------------------------------------------------------------
__global__ void __launch_bounds__(256, 4) proj_out_kernel(const float* __restrict__ emb,
                                                          const float* __restrict__ rb,
                                                          const v8h* __restrict__ afragO,
                                                          float* __restrict__ outb) {
  int tid = threadIdx.x, wave = tid >> 6, lane = tid & 63;
  int lr = lane & 15, lg = lane >> 4;
  int tb = blockIdx.x >> 1, mb = blockIdx.x & 1;
  int t0 = tb * 64 + wave * 16;
  int b  = t0 >> 12;
  const float* ebase = emb + (size_t)b * CIN * T_ + (t0 & (T_ - 1)) + lr;

  v4f acc[16];
#pragma unroll
  for (int mt = 0; mt < 16; mt++) acc[mt] = (v4f){0.f, 0.f, 0.f, 0.f};

  for (int ks = 0; ks < 24; ks++) {
    float e[8];
    if (ks < 16) {
#pragma unroll
      for (int j = 0; j < 8; j++)
        e[j] = ebase[(size_t)(ks * 32 + lg * 8 + j) * T_];
    } else {
      const float* rrow = rb + (size_t)(t0 + lr) * D_ + (ks - 16) * 32 + lg * 8;
      float4 f0 = *(const float4*)rrow, f1 = *(const float4*)(rrow + 4);
      e[0] = f0.x; e[1] = f0.y; e[2] = f0.z; e[3] = f0.w;
      e[4] = f1.x; e[5] = f1.y; e[6] = f1.z; e[7] = f1.w;
    }
    v8h Bh;
#pragma unroll
    for (int j = 0; j < 8; j++) Bh[j] = (_Float16)e[j];
#pragma unroll
    for (int mt = 0; mt < 16; mt++) {
      v8h Ah = afragO[(((size_t)(mb * 16 + mt) * 24 + ks) * 64 + lane) * 2];
      acc[mt] = __builtin_amdgcn_mfma_f32_16x16x32_f16(Ah, Bh, acc[mt], 0, 0, 0);
    }
  }
  float* op = outb + (size_t)b * CIN * T_ + (t0 & (T_ - 1)) + lr;
#pragma unroll
  for (int mt = 0; mt < 16; mt++)
#pragma unroll
    for (int r = 0; r < 4; r++)
      op[(size_t)((mt + mb * 16) * 16 + lg * 4 + r) * T_] = acc[mt][r];
}

// ---------------------------------------------------------------------------
// merge helper (proven round-6/7 code; wave 0..3, candL[64][6])
// ---------------------------------------------------------------------------
__device__ __forceinline__ void merge_save(unsigned b1[4], unsigned b2[4], unsigned b3[4],
                                           int half, int wave, int lg, int lr,
                                           int (*candL)[6]) {
#pragma unroll
  for (int rI = 0; rI < 4; rI++) {
    unsigned k1 = b1[rI], k2 = b2[rI], k3 = b3[rI];
    int n1 = (int)(k1 & 127u) * 16 + lr;
    int n2 = (int)(k2 & 127u) * 16 + lr;
    int n3 = (int)(k3 & 127u) * 16 + lr;
    int o0 = 0, o1 = 0, o2v = 0;
#pragma unroll
    for (int round = 0; round < 3; round++) {
      unsigned mk = k1; int mn = n1;
#pragma unroll
      for (int st = 1; st < 16; st <<= 1) {
        unsigned ok = (unsigned)__shfl_xor((int)mk, st);
        int      on = __shfl_xor(mn, st);
        bool t = (ok < mk) || (ok == mk && on < mn);
        mk = t ? ok : mk; mn = t ? on : mn;
      }
      if (round == 0) o0 = mn; else if (round == 1) o1 = mn; else o2v = mn;
      bool own = (k1 == mk) && (n1 == mn);
      k1 = own ? k2 : k1; n1 = own ? n2 : n1;
      k2 = own ? k3 : k2; n2 = own ? n3 : n2;
      k3 = own ? 0xFFFFFFFFu : k3; n3 = own ? 0x7fffffff : n3;
    }
    if (lr == 0) {
      int* cp = candL[wave * 16 + lg * 4 + rI] + half * 3;
      cp[0] = o0; cp[1] = o1; cp[2] = o2v;
    }
  }
}

// ---------------------------------------------------------------------------
// Mega RVQ v9: 256-thr geometry (VGPR 160, no spill — proven r15) with
// 2-chunk staging groups (buf 16 KB, dbuf 32 KB + cand ~= 34 KB/block):
// r15's 64 KB LDS allowed only 1 block/CU (12% occupancy, +376 us); 34 KB
// fits 2 blocks/CU at grid 512 -> 8 waves/CU with cross-block barrier
// overlap and no scratch.  Scan/select/update math byte-identical.
// ---------------------------------------------------------------------------
__global__ void __launch_bounds__(256)
rvq_mega_kernel(const _Float16* __restrict__ ehs,
                const float* __restrict__ nrm,
                const float* __restrict__ inv_,
                const float* __restrict__ usage,
                const float* __restrict__ embed_sum,
                float* __restrict__ rb,
                float* __restrict__ codes_f) {
  __shared__ v8h ldsB[2][1024];   // 32 KB: 2 buf x 2 chunks x 4096 f16
  __shared__ int candL[64][6];

  int tid  = threadIdx.x;
  int wave = tid >> 6, lane = tid & 63;
  int lr = lane & 15, lg = lane >> 4;
  int wbase = blockIdx.x * 64 + wave * 16;
  int token = wbase + lr;

  // prologue: load residual (A-frag layout), once
  float r64[64];
  {
    const float* rrow = rb + (size_t)token * D_ + lg * 8;
#pragma unroll
    for (int c = 0; c < 8; c++) {
      float4 f0 = *(const float4*)(rrow + c * 32);
      float4 f1 = *(const float4*)(rrow + c * 32 + 4);
      r64[c * 8 + 0] = f0.x; r64[c * 8 + 1] = f0.y;
      r64[c * 8 + 2] = f0.z; r64[c * 8 + 3] = f0.w;
      r64[c * 8 + 4] = f1.x; r64[c * 8 + 5] = f1.y;
      r64[c * 8 + 6] = f1.z; r64[c * 8 + 7] = f1.w;
    }
  }

  for (int k = 0; k < K_; k++) {
    // A fragments from register residual (pure VALU)
    v8h A[8];
#pragma unroll
    for (int c = 0; c < 8; c++) {
      v8h a;
#pragma unroll
      for (int j = 0; j < 8; j++) a[j] = (_Float16)r64[c * 8 + j];
      A[c] = a;
    }

    const v8h* src = (const v8h*)(ehs + (size_t)k * 2 * (64 * 4096));

    // stage group 0 (2 chunks = 1024 v8h) via async global->LDS
#pragma unroll
    for (int q = 0; q < 4; q++) {
      int idx = tid + q * 256;
      __builtin_amdgcn_global_load_lds(
          (__attribute__((address_space(1))) void*)(void*)(src + idx),
          (__attribute__((address_space(3))) void*)(&ldsB[0][idx]), 16, 0, 0);
    }

    unsigned b1[4], b2[4], b3[4];
#pragma unroll
    for (int i = 0; i < 4; i++) { b1[i] = b2[i] = b3[i] = 0xFFFFFFFFu; }
    const float* nrm_k = nrm + (size_t)k * N_;
    __syncthreads();   // drains vmcnt -> buf0 ready

    for (int g = 0; g < 64; g++) {
      int cur = g & 1;
      if (g + 1 < 64) {                                  // issue-early (T14)
        const v8h* gsrc = src + (size_t)(g + 1) * 1024;
#pragma unroll
        for (int q = 0; q < 4; q++) {
          int idx = tid + q * 256;
          __builtin_amdgcn_global_load_lds(
              (__attribute__((address_space(1))) void*)(void*)(gsrc + idx),
              (__attribute__((address_space(3))) void*)(&ldsB[cur ^ 1][idx]), 16, 0, 0);
        }
      }

      v4f acc[2];
#pragma unroll
      for (int m = 0; m < 2; m++) acc[m] = (v4f){0.f, 0.f, 0.f, 0.f};
#pragma unroll
      for (int c = 0; c < 8; c++) {
#pragma unroll
        for (int m = 0; m < 2; m++) {
          v8h Bf = ldsB[cur][m * 512 + (c * 4 + lg) * 16 + lr];
          acc[m] = __builtin_amdgcn_mfma_f32_16x16x32_f16(A[c], Bf, acc[m], 0, 0, 0);
        }
      }
#pragma unroll
      for (int m = 0; m < 2; m++) {
        unsigned cg = (unsigned)(2 * g + m);
        float nv = nrm_k[cg * 16 + lr];                  // biased +2048 -> s > 0
#pragma unroll
        for (int j = 0; j < 4; j++) {
          float s = fmaf(-2.0f, acc[m][j], nv);
          unsigned pk = (__float_as_uint(s) & 0xFFFFFF80u) | cg;
          unsigned t = umx(b1[j], pk);
          unsigned u = umx(b2[j], pk);
          b1[j] = umn(b1[j], pk);
          b2[j] = umn(b2[j], t);
          b3[j] = umn(b3[j], u);
        }
      }
      if (g == 31) {                                     // end of half 0
        merge_save(b1, b2, b3, 0, wave, lg, lr, candL);
#pragma unroll
        for (int i = 0; i < 4; i++) { b1[i] = b2[i] = b3[i] = 0xFFFFFFFFu; }
      }
      __syncthreads();   // all reads of cur done; next-buf DMA drained
    }
    merge_save(b1, b2, b3, 1, wave, lg, lr, candL);
    __syncthreads();

    // -------- select: 4 lg-lanes per token (lr), 64 dims each --------
    const float* es_k  = embed_sum + (size_t)k * N_ * D_;
    const float* us_k  = usage + (size_t)k * N_;
    const float* inv_k = inv_  + (size_t)k * N_;

    int c6[6];
#pragma unroll
    for (int i = 0; i < 6; i++) c6[i] = candL[wave * 16 + lr][i];

    float dots[6];
#pragma unroll
    for (int i = 0; i < 6; i++) {
      const float* sr = es_k + (size_t)c6[i] * D_ + lg * 8;
      float a = 0.f;
#pragma unroll
      for (int c = 0; c < 8; c++) {
        float4 s0 = *(const float4*)(sr + c * 32);
        float4 s1 = *(const float4*)(sr + c * 32 + 4);
        a += r64[c * 8 + 0] * s0.x + r64[c * 8 + 1] * s0.y
           + r64[c * 8 + 2] * s0.z + r64[c * 8 + 3] * s0.w
           + r64[c * 8 + 4] * s1.x + r64[c * 8 + 5] * s1.y
           + r64[c * 8 + 6] * s1.z + r64[c * 8 + 7] * s1.w;
      }
      dots[i] = a;
    }
#pragma unroll
    for (int i = 0; i < 6; i++) {
      dots[i] += __shfl_xor(dots[i], 16);
      dots[i] += __shfl_xor(dots[i], 32);
    }

    float bs = FLT_MAX, bv2 = FLT_MAX; int bn = 0x7fffffff, bn2 = 0x7fffffff;
#pragma unroll
    for (int i = 0; i < 6; i++) {
      int n = c6[i];
      float s = nrm_k[n] - 2.0f * inv_k[n] * dots[i];
      bool better = (s < bs) || (s == bs && n < bn);
      bool second = (s < bv2) || (s == bv2 && n < bn2);
      if (better)      { bv2 = bs; bn2 = bn; bs = s; bn = n; }
      else if (second) { bv2 = s;  bn2 = n; }
    }
    int winner = bn;
    if (bv2 - bs < 0.5f && bn2 != bn) {
      double sc[2]; int nn[2] = { bn, bn2 };
#pragma unroll
      for (int cI = 0; cI < 2; cI++) {
        double u = fmax((double)us_k[nn[cI]], 1e-5);
        double uinv = 1.0 / u;
        const float* srow = es_k + (size_t)nn[cI] * D_ + lg * 8;
        double dotre = 0.0, ee = 0.0;
#pragma unroll
        for (int c = 0; c < 8; c++) {
          float4 s0 = *(const float4*)(srow + c * 32);
          float4 s1 = *(const float4*)(srow + c * 32 + 4);
          double e0 = (double)s0.x * uinv, e1 = (double)s0.y * uinv;
          double e2 = (double)s0.z * uinv, e3 = (double)s0.w * uinv;
          double e4 = (double)s1.x * uinv, e5 = (double)s1.y * uinv;
          double e6 = (double)s1.z * uinv, e7 = (double)s1.w * uinv;
          dotre += (double)r64[c * 8 + 0] * e0 + (double)r64[c * 8 + 1] * e1
                 + (double)r64[c * 8 + 2] * e2 + (double)r64[c * 8 + 3] * e3
                 + (double)r64[c * 8 + 4] * e4 + (double)r64[c * 8 + 5] * e5
                 + (double)r64[c * 8 + 6] * e6 + (double)r64[c * 8 + 7] * e7;
          ee += e0 * e0 + e1 * e1 + e2 * e2 + e3 * e3
              + e4 * e4 + e5 * e5 + e6 * e6 + e7 * e7;
        }
        dotre += __shfl_xor(dotre, 16); dotre += __shfl_xor(dotre, 32);
        ee    += __shfl_xor(ee, 16);    ee    += __shfl_xor(ee, 32);
        sc[cI] = ee - 2.0 * dotre;
      }
      if (sc[1] < sc[0] || (sc[1] == sc[0] && nn[1] < nn[0])) winner = nn[1];
    }

    // residual update in registers (exact f32 s/um math)
    float um = fmaxf(us_k[winner], EPSF);
    const float* sw = es_k + (size_t)winner * D_ + lg * 8;
#pragma unroll
    for (int c = 0; c < 8; c++) {
      float4 s0 = *(const float4*)(sw + c * 32);
      float4 s1 = *(const float4*)(sw + c * 32 + 4);
      r64[c * 8 + 0] -= s0.x / um; r64[c * 8 + 1] -= s0.y / um;
      r64[c * 8 + 2] -= s0.z / um; r64[c * 8 + 3] -= s0.w / um;
      r64[c * 8 + 4] -= s1.x / um; r64[c * 8 + 5] -= s1.y / um;
      r64[c * 8 + 6] -= s1.z / um; r64[c * 8 + 7] -= s1.w / um;
    }
    if (lg == 0) codes_f[(size_t)k * BT + token] = (float)winner;
    // next step's candL write (g==31) is gated by the pre-g-loop barrier.
  }

  // epilogue: write final residual back for proj_out
  {
    float* wrow = rb + (size_t)token * D_ + lg * 8;
#pragma unroll
    for (int c = 0; c < 8; c++) {
      float4 f0 = make_float4(r64[c * 8 + 0], r64[c * 8 + 1],
                              r64[c * 8 + 2], r64[c * 8 + 3]);
      float4 f1 = make_float4(r64[c * 8 + 4], r64[c * 8 + 5],
                              r64[c * 8 + 6], r64[c * 8 + 7]);
      *(float4*)(wrow + c * 32)     = f0;
      *(float4*)(wrow + c * 32 + 4) = f1;
    }
  }
}

// ---------------------------------------------------------------------------
extern "C" void kernel_launch(void* const* d_in, const int* in_sizes, int n_in,
                              void* d_out, int out_size, void* d_ws, size_t ws_size,
                              hipStream_t stream) {
  const float* emb       = (const float*)d_in[0];
  const float* w_in      = (const float*)d_in[1];
  const float* w_out     = (const float*)d_in[2];
  const float* embed_sum = (const float*)d_in[3];
  const float* usage     = (const float*)d_in[4];

  float* outp    = (float*)d_out;
  float* codes_f = outp;
  float* proj_o  = outp + (size_t)K_ * BT;

  float* rb   = (float*)d_ws;                          // BT*D f32 (33.55 MB)
  float* inv  = rb + (size_t)BT * D_;                  // K*N
  float* nrm  = inv + (size_t)K_ * N_;                 // K*N
  int*   cand = (int*)(nrm + (size_t)K_ * N_);         // (unused gap, kept)
  _Float16* ehs = (_Float16*)(cand + (size_t)BT * 6);  // K*N*D f16 (8.39 MB)
  v8h* afragX = (v8h*)(ehs + (size_t)K_ * N_ * D_);    // 512 KB
  float* wc   = (float*)(afragX + 16 * 16 * 64 * 2);   // 1 MB
  v8h* afragO = (v8h*)(wc + 512 * 512);                // 1.5 MB

  hipLaunchKernelGGL(wprep_x_kernel, dim3(256), dim3(64), 0, stream, w_in, afragX);
  hipLaunchKernelGGL(wc_kernel, dim3(1024), dim3(256), 0, stream, w_out, w_in, wc);
  hipLaunchKernelGGL(wprep_o_kernel, dim3(768), dim3(64), 0, stream, wc, w_out, afragO);
  hipLaunchKernelGGL(prep_kernel, dim3(K_ * N_ / 4), dim3(256), 0, stream,
                     embed_sum, usage, inv, nrm, ehs);
  hipLaunchKernelGGL(proj_x_kernel, dim3(BT / 32), dim3(256), 0, stream,
                     emb, afragX, rb);
  hipLaunchKernelGGL(rvq_mega_kernel, dim3(BT / 64), dim3(256), 0, stream,
                     ehs, nrm, inv, usage, embed_sum, rb, codes_f);
  hipLaunchKernelGGL(proj_out_kernel, dim3(BT / 32), dim3(256), 0, stream,
                     emb, rb, afragO, proj_o);
}

// Round 17
// 878.964 us; speedup vs baseline: 1.8097x; 1.8097x over previous
//
#include <hip/hip_runtime.h>
#include <float.h>
#include <math.h>

#define EPSF 1e-5f
#define NRM_BIAS 2048.0f

constexpr int B_  = 8;
constexpr int CIN = 512;
constexpr int T_  = 4096;
constexpr int K_  = 8;
constexpr int N_  = 2048;
constexpr int D_  = 256;
constexpr int BT  = B_ * T_;          // 32768 tokens

typedef _Float16 v8h __attribute__((ext_vector_type(8)));
typedef _Float16 v4h __attribute__((ext_vector_type(4)));
typedef float    v4f __attribute__((ext_vector_type(4)));

static __device__ __forceinline__ unsigned umn(unsigned a, unsigned b) { return a < b ? a : b; }
static __device__ __forceinline__ unsigned umx(unsigned a, unsigned b) { return a > b ? a : b; }

// ---------------------------------------------------------------------------
// prep: inv = 1/clamp(u), nrm = sum_d e^2 + NRM_BIAS; f16 codebook in
// MFMA-fragment-swizzled order (proven, unchanged).
// ---------------------------------------------------------------------------
__global__ void __launch_bounds__(256) prep_kernel(const float* __restrict__ embed_sum,
                                                   const float* __restrict__ usage,
                                                   float* __restrict__ inv,
                                                   float* __restrict__ nrm,
                                                   _Float16* __restrict__ ehs) {
  int w    = threadIdx.x >> 6;
  int lane = threadIdx.x & 63;
  int kn   = blockIdx.x * 4 + w;
  int k    = kn >> 11, n = kn & (N_ - 1);
  const float* s = embed_sum + (size_t)kn * D_;
  float um = fmaxf(usage[kn], EPSF);
  float4 sv = *(const float4*)(s + lane * 4);
  float e0 = sv.x / um, e1 = sv.y / um, e2 = sv.z / um, e3 = sv.w / um;
  float v = e0 * e0 + e1 * e1 + e2 * e2 + e3 * e3;

  int half = n >> 10, chunk = (n >> 4) & 63, r = n & 15;
  int cg = lane >> 1, sub = lane & 1;
  v4h h4; h4[0] = (_Float16)e0; h4[1] = (_Float16)e1;
  h4[2] = (_Float16)e2; h4[3] = (_Float16)e3;
  size_t off16 = ((size_t)((k * 2 + half) * 64 + chunk)) * 4096
               + (size_t)(cg * 16 + r) * 8 + (size_t)sub * 4;
  *(v4h*)(ehs + off16) = h4;

  for (int off = 32; off > 0; off >>= 1) v += __shfl_down(v, off);
  if (lane == 0) { inv[kn] = 1.0f / um; nrm[kn] = v + NRM_BIAS; }
}

// ---------------------------------------------------------------------------
// wprep_x / wc / wprep_o (proven, unchanged)
// ---------------------------------------------------------------------------
__global__ void __launch_bounds__(64) wprep_x_kernel(const float* __restrict__ w_in,
                                                     v8h* __restrict__ afragX) {
  int lane = threadIdx.x;
  int mt = blockIdx.x >> 4, kstep = blockIdx.x & 15;
  int m = mt * 16 + (lane & 15), k0 = kstep * 32 + (lane >> 4) * 8;
  const float* src = w_in + (size_t)m * CIN + k0;
  float4 f0 = *(const float4*)src, f1 = *(const float4*)(src + 4);
  float e[8] = {f0.x, f0.y, f0.z, f0.w, f1.x, f1.y, f1.z, f1.w};
  v8h h, l;
#pragma unroll
  for (int j = 0; j < 8; j++) {
    _Float16 hh = (_Float16)e[j];
    h[j] = hh; l[j] = (_Float16)(e[j] - (float)hh);
  }
  v8h* dst = afragX + ((size_t)blockIdx.x * 64 + lane) * 2;
  dst[0] = h; dst[1] = l;
}

__global__ void __launch_bounds__(256) wc_kernel(const float* __restrict__ w_out,
                                                 const float* __restrict__ w_in,
                                                 float* __restrict__ wc) {
  int c  = blockIdx.x >> 1;
  int cp = (blockIdx.x & 1) * 256 + threadIdx.x;
  float acc = 0.f;
  for (int d = 0; d < D_; d++)
    acc += w_out[(size_t)c * D_ + d] * w_in[(size_t)d * CIN + cp];
  wc[(size_t)c * CIN + cp] = acc;
}

__global__ void __launch_bounds__(64) wprep_o_kernel(const float* __restrict__ wc,
                                                     const float* __restrict__ w_out,
                                                     v8h* __restrict__ afragO) {
  int lane = threadIdx.x;
  int mt = blockIdx.x / 24, kstep = blockIdx.x % 24;
  int m = mt * 16 + (lane & 15), k0 = kstep * 32 + (lane >> 4) * 8;
  float e[8];
  if (k0 < CIN) {
    const float* s = wc + (size_t)m * CIN + k0;
#pragma unroll
    for (int j = 0; j < 8; j++) e[j] = s[j];
  } else {
    const float* s = w_out + (size_t)m * D_ + (k0 - CIN);
#pragma unroll
    for (int j = 0; j < 8; j++) e[j] = -s[j];
  }
  v8h h, l;
#pragma unroll
  for (int j = 0; j < 8; j++) {
    _Float16 hh = (_Float16)e[j];
    h[j] = hh; l[j] = (_Float16)(e[j] - (float)hh);
  }
  v8h* dst = afragO + ((size_t)blockIdx.x * 64 + lane) * 2;
  dst[0] = h; dst[1] = l;
}

// ---------------------------------------------------------------------------
// proj_x: split-3 f16 MFMA, m-split x2 (proven round-6 kernel, unchanged)
// ---------------------------------------------------------------------------
__global__ void __launch_bounds__(256, 4) proj_x_kernel(const float* __restrict__ emb,
                                                        const v8h* __restrict__ afragX,
                                                        float* __restrict__ rb) {
  int tid = threadIdx.x, wave = tid >> 6, lane = tid & 63;
  int lr = lane & 15, lg = lane >> 4;
  int tb = blockIdx.x >> 1, nb = blockIdx.x & 1;
  int t0 = tb * 64 + wave * 16;
  int b  = t0 >> 12;
  const float* ebase = emb + (size_t)b * CIN * T_ + (t0 & (T_ - 1)) + lr;

  v4f acc[8];
#pragma unroll
  for (int nt = 0; nt < 8; nt++) acc[nt] = (v4f){0.f, 0.f, 0.f, 0.f};

  for (int ks = 0; ks < 16; ks++) {
    float e[8];
#pragma unroll
    for (int j = 0; j < 8; j++)
      e[j] = ebase[(size_t)(ks * 32 + lg * 8 + j) * T_];
    v8h Eh, El;
#pragma unroll
    for (int j = 0; j < 8; j++) {
      _Float16 hh = (_Float16)e[j];
      Eh[j] = hh; El[j] = (_Float16)(e[j] - (float)hh);
    }
    const v8h* ap = afragX + ((size_t)ks * 64 + lane) * 2;
#pragma unroll
    for (int nt = 0; nt < 8; nt++) {
      int mt = nb * 8 + nt;
      v8h Wh = ap[(size_t)mt * 2048];
      v8h Wl = ap[(size_t)mt * 2048 + 1];
      acc[nt] = __builtin_amdgcn_mfma_f32_16x16x32_f16(Eh, Wh, acc[nt], 0, 0, 0);
      acc[nt] = __builtin_amdgcn_mfma_f32_16x16x32_f16(El, Wh, acc[nt], 0, 0, 0);
      acc[nt] = __builtin_amdgcn_mfma_f32_16x16x32_f16(Eh, Wl, acc[nt], 0, 0, 0);
    }
  }
#pragma unroll
  for (int nt = 0; nt < 8; nt++)
#pragma unroll
    for (int r = 0; r < 4; r++)
      rb[(size_t)(t0 + lg * 4 + r) * D_ + (nb * 8 + nt) * 16 + lr] = acc[nt][r];
}

// ---------------------------------------------------------------------------
// proj_out (proven round-5 kernel, unchanged)
// ---------------------------------------------------------------------------
__global__ void __launch_bounds__(256, 4) proj_out_kernel(const float* __restrict__ emb,
                                                          const float* __restrict__ rb,
                                                          const v8h* __restrict__ afragO,
                                                          float* __restrict__ outb) {
  int tid = threadIdx.x, wave = tid >> 6, lane = tid & 63;
  int lr = lane & 15, lg = lane >> 4;
  int tb = blockIdx.x >> 1, mb = blockIdx.x & 1;
  int t0 = tb * 64 + wave * 16;
  int b  = t0 >> 12;
  const float* ebase = emb + (size_t)b * CIN * T_ + (t0 & (T_ - 1)) + lr;

  v4f acc[16];
#pragma unroll
  for (int mt = 0; mt < 16; mt++) acc[mt] = (v4f){0.f, 0.f, 0.f, 0.f};

  for (int ks = 0; ks < 24; ks++) {
    float e[8];
    if (ks < 16) {
#pragma unroll
      for (int j = 0; j < 8; j++)
        e[j] = ebase[(size_t)(ks * 32 + lg * 8 + j) * T_];
    } else {
      const float* rrow = rb + (size_t)(t0 + lr) * D_ + (ks - 16) * 32 + lg * 8;
      float4 f0 = *(const float4*)rrow, f1 = *(const float4*)(rrow + 4);
      e[0] = f0.x; e[1] = f0.y; e[2] = f0.z; e[3] = f0.w;
      e[4] = f1.x; e[5] = f1.y; e[6] = f1.z; e[7] = f1.w;
    }
    v8h Bh;
#pragma unroll
    for (int j = 0; j < 8; j++) Bh[j] = (_Float16)e[j];
#pragma unroll
    for (int mt = 0; mt < 16; mt++) {
      v8h Ah = afragO[(((size_t)(mb * 16 + mt) * 24 + ks) * 64 + lane) * 2];
      acc[mt] = __builtin_amdgcn_mfma_f32_16x16x32_f16(Ah, Bh, acc[mt], 0, 0, 0);
    }
  }
  float* op = outb + (size_t)b * CIN * T_ + (t0 & (T_ - 1)) + lr;
#pragma unroll
  for (int mt = 0; mt < 16; mt++)
#pragma unroll
    for (int r = 0; r < 4; r++)
      op[(size_t)((mt + mb * 16) * 16 + lg * 4 + r) * T_] = acc[mt][r];
}

// ---------------------------------------------------------------------------
// merge helper (proven round-6/7 code, unchanged; candL[128][6])
// ---------------------------------------------------------------------------
__device__ __forceinline__ void merge_save(unsigned b1[4], unsigned b2[4], unsigned b3[4],
                                           int half, int wave, int lg, int lr,
                                           int (*candL)[6]) {
#pragma unroll
  for (int rI = 0; rI < 4; rI++) {
    unsigned k1 = b1[rI], k2 = b2[rI], k3 = b3[rI];
    int n1 = (int)(k1 & 127u) * 16 + lr;
    int n2 = (int)(k2 & 127u) * 16 + lr;
    int n3 = (int)(k3 & 127u) * 16 + lr;
    int o0 = 0, o1 = 0, o2v = 0;
#pragma unroll
    for (int round = 0; round < 3; round++) {
      unsigned mk = k1; int mn = n1;
#pragma unroll
      for (int st = 1; st < 16; st <<= 1) {
        unsigned ok = (unsigned)__shfl_xor((int)mk, st);
        int      on = __shfl_xor(mn, st);
        bool t = (ok < mk) || (ok == mk && on < mn);
        mk = t ? ok : mk; mn = t ? on : mn;
      }
      if (round == 0) o0 = mn; else if (round == 1) o1 = mn; else o2v = mn;
      bool own = (k1 == mk) && (n1 == mn);
      k1 = own ? k2 : k1; n1 = own ? n2 : n1;
      k2 = own ? k3 : k2; n2 = own ? n3 : n2;
      k3 = own ? 0xFFFFFFFFu : k3; n3 = own ? 0x7fffffff : n3;
    }
    if (lr == 0) {
      int* cp = candL[wave * 16 + lg * 4 + rI] + half * 3;
      cp[0] = o0; cp[1] = o1; cp[2] = o2v;
    }
  }
}

// ---------------------------------------------------------------------------
// Mega RVQ v10 = round-14 (best: 787 us) + 8-chunk staging groups:
//  - 2 x 64 KB dbuf (LDS ~134 KB < 160; 512-thr = 1 block/CU regardless,
//    so no occupancy cost).  Barriers 274 -> 146 total (16/step + 2).
//  - 8 chunks processed as TWO 4-chunk sub-batches with the same acc[4]
//    register profile as r14 -> VGPR/spill picture unchanged.
//  - Scan/insert/merge/select/update math byte-identical to r14.
// ---------------------------------------------------------------------------
__global__ void __launch_bounds__(512)
rvq_mega_kernel(const _Float16* __restrict__ ehs,
                const float* __restrict__ nrm,
                const float* __restrict__ inv_,
                const float* __restrict__ usage,
                const float* __restrict__ embed_sum,
                float* __restrict__ rb,
                float* __restrict__ codes_f) {
  __shared__ v8h ldsB[2][4096];   // 128 KB: 2 buf x 8 chunks x 4096 f16
  __shared__ int candL[128][6];

  int tid  = threadIdx.x;
  int wave = tid >> 6, lane = tid & 63;
  int lr = lane & 15, lg = lane >> 4;
  int wbase = blockIdx.x * 128 + wave * 16;
  int token = wbase + lr;

  // prologue: load residual (A-frag layout), once
  float r64[64];
  {
    const float* rrow = rb + (size_t)token * D_ + lg * 8;
#pragma unroll
    for (int c = 0; c < 8; c++) {
      float4 f0 = *(const float4*)(rrow + c * 32);
      float4 f1 = *(const float4*)(rrow + c * 32 + 4);
      r64[c * 8 + 0] = f0.x; r64[c * 8 + 1] = f0.y;
      r64[c * 8 + 2] = f0.z; r64[c * 8 + 3] = f0.w;
      r64[c * 8 + 4] = f1.x; r64[c * 8 + 5] = f1.y;
      r64[c * 8 + 6] = f1.z; r64[c * 8 + 7] = f1.w;
    }
  }

  for (int k = 0; k < K_; k++) {
    // A fragments from register residual (pure VALU)
    v8h A[8];
#pragma unroll
    for (int c = 0; c < 8; c++) {
      v8h a;
#pragma unroll
      for (int j = 0; j < 8; j++) a[j] = (_Float16)r64[c * 8 + j];
      A[c] = a;
    }

    const v8h* src = (const v8h*)(ehs + (size_t)k * 2 * (64 * 4096));

    // stage group 0 (8 chunks = 4096 v8h) via async global->LDS
#pragma unroll
    for (int q = 0; q < 8; q++) {
      int idx = tid + q * 512;
      __builtin_amdgcn_global_load_lds(
          (__attribute__((address_space(1))) void*)(void*)(src + idx),
          (__attribute__((address_space(3))) void*)(&ldsB[0][idx]), 16, 0, 0);
    }

    unsigned b1[4], b2[4], b3[4];
#pragma unroll
    for (int i = 0; i < 4; i++) { b1[i] = b2[i] = b3[i] = 0xFFFFFFFFu; }
    const float* nrm_k = nrm + (size_t)k * N_;
    __syncthreads();   // drains vmcnt -> buf0 ready

    for (int g = 0; g < 16; g++) {
      int cur = g & 1;
      if (g + 1 < 16) {                                  // issue-early (T14)
        const v8h* gsrc = src + (size_t)(g + 1) * 4096;
#pragma unroll
        for (int q = 0; q < 8; q++) {
          int idx = tid + q * 512;
          __builtin_amdgcn_global_load_lds(
              (__attribute__((address_space(1))) void*)(void*)(gsrc + idx),
              (__attribute__((address_space(3))) void*)(&ldsB[cur ^ 1][idx]), 16, 0, 0);
        }
      }

#pragma unroll
      for (int s = 0; s < 2; s++) {                      // two 4-chunk batches
        v4f acc[4];
#pragma unroll
        for (int m = 0; m < 4; m++) acc[m] = (v4f){0.f, 0.f, 0.f, 0.f};
#pragma unroll
        for (int c = 0; c < 8; c++) {
#pragma unroll
          for (int m = 0; m < 4; m++) {
            v8h Bf = ldsB[cur][(s * 4 + m) * 512 + (c * 4 + lg) * 16 + lr];
            acc[m] = __builtin_amdgcn_mfma_f32_16x16x32_f16(A[c], Bf, acc[m], 0, 0, 0);
          }
        }
#pragma unroll
        for (int m = 0; m < 4; m++) {
          unsigned cg = (unsigned)(8 * g + s * 4 + m);
          float nv = nrm_k[cg * 16 + lr];                // biased +2048 -> s > 0
#pragma unroll
          for (int j = 0; j < 4; j++) {
            float sv = fmaf(-2.0f, acc[m][j], nv);
            unsigned pk = (__float_as_uint(sv) & 0xFFFFFF80u) | cg;
            unsigned t = umx(b1[j], pk);
            unsigned u = umx(b2[j], pk);
            b1[j] = umn(b1[j], pk);
            b2[j] = umn(b2[j], t);
            b3[j] = umn(b3[j], u);
          }
        }
      }
      if (g == 7) {                                      // end of half 0
        merge_save(b1, b2, b3, 0, wave, lg, lr, candL);
#pragma unroll
        for (int i = 0; i < 4; i++) { b1[i] = b2[i] = b3[i] = 0xFFFFFFFFu; }
      }
      __syncthreads();   // all reads of cur done; next-buf DMA drained
    }
    merge_save(b1, b2, b3, 1, wave, lg, lr, candL);
    __syncthreads();

    // -------- select: 4 lg-lanes per token (lr), 64 dims each --------
    const float* es_k  = embed_sum + (size_t)k * N_ * D_;
    const float* us_k  = usage + (size_t)k * N_;
    const float* inv_k = inv_  + (size_t)k * N_;

    int c6[6];
#pragma unroll
    for (int i = 0; i < 6; i++) c6[i] = candL[wave * 16 + lr][i];

    float dots[6];
#pragma unroll
    for (int i = 0; i < 6; i++) {
      const float* sr = es_k + (size_t)c6[i] * D_ + lg * 8;
      float a = 0.f;
#pragma unroll
      for (int c = 0; c < 8; c++) {
        float4 s0 = *(const float4*)(sr + c * 32);
        float4 s1 = *(const float4*)(sr + c * 32 + 4);
        a += r64[c * 8 + 0] * s0.x + r64[c * 8 + 1] * s0.y
           + r64[c * 8 + 2] * s0.z + r64[c * 8 + 3] * s0.w
           + r64[c * 8 + 4] * s1.x + r64[c * 8 + 5] * s1.y
           + r64[c * 8 + 6] * s1.z + r64[c * 8 + 7] * s1.w;
      }
      dots[i] = a;
    }
#pragma unroll
    for (int i = 0; i < 6; i++) {
      dots[i] += __shfl_xor(dots[i], 16);
      dots[i] += __shfl_xor(dots[i], 32);
    }

    float bs = FLT_MAX, bv2 = FLT_MAX; int bn = 0x7fffffff, bn2 = 0x7fffffff;
#pragma unroll
    for (int i = 0; i < 6; i++) {
      int n = c6[i];
      float s = nrm_k[n] - 2.0f * inv_k[n] * dots[i];
      bool better = (s < bs) || (s == bs && n < bn);
      bool second = (s < bv2) || (s == bv2 && n < bn2);
      if (better)      { bv2 = bs; bn2 = bn; bs = s; bn = n; }
      else if (second) { bv2 = s;  bn2 = n; }
    }
    int winner = bn;
    if (bv2 - bs < 0.5f && bn2 != bn) {
      double sc[2]; int nn[2] = { bn, bn2 };
#pragma unroll
      for (int cI = 0; cI < 2; cI++) {
        double u = fmax((double)us_k[nn[cI]], 1e-5);
        double uinv = 1.0 / u;
        const float* srow = es_k + (size_t)nn[cI] * D_ + lg * 8;
        double dotre = 0.0, ee = 0.0;
#pragma unroll
        for (int c = 0; c < 8; c++) {
          float4 s0 = *(const float4*)(srow + c * 32);
          float4 s1 = *(const float4*)(srow + c * 32 + 4);
          double e0 = (double)s0.x * uinv, e1 = (double)s0.y * uinv;
          double e2 = (double)s0.z * uinv, e3 = (double)s0.w * uinv;
          double e4 = (double)s1.x * uinv, e5 = (double)s1.y * uinv;
          double e6 = (double)s1.z * uinv, e7 = (double)s1.w * uinv;
          dotre += (double)r64[c * 8 + 0] * e0 + (double)r64[c * 8 + 1] * e1
                 + (double)r64[c * 8 + 2] * e2 + (double)r64[c * 8 + 3] * e3
                 + (double)r64[c * 8 + 4] * e4 + (double)r64[c * 8 + 5] * e5
                 + (double)r64[c * 8 + 6] * e6 + (double)r64[c * 8 + 7] * e7;
          ee += e0 * e0 + e1 * e1 + e2 * e2 + e3 * e3
              + e4 * e4 + e5 * e5 + e6 * e6 + e7 * e7;
        }
        dotre += __shfl_xor(dotre, 16); dotre += __shfl_xor(dotre, 32);
        ee    += __shfl_xor(ee, 16);    ee    += __shfl_xor(ee, 32);
        sc[cI] = ee - 2.0 * dotre;
      }
      if (sc[1] < sc[0] || (sc[1] == sc[0] && nn[1] < nn[0])) winner = nn[1];
    }

    // residual update in registers (exact f32 s/um math)
    float um = fmaxf(us_k[winner], EPSF);
    const float* sw = es_k + (size_t)winner * D_ + lg * 8;
#pragma unroll
    for (int c = 0; c < 8; c++) {
      float4 s0 = *(const float4*)(sw + c * 32);
      float4 s1 = *(const float4*)(sw + c * 32 + 4);
      r64[c * 8 + 0] -= s0.x / um; r64[c * 8 + 1] -= s0.y / um;
      r64[c * 8 + 2] -= s0.z / um; r64[c * 8 + 3] -= s0.w / um;
      r64[c * 8 + 4] -= s1.x / um; r64[c * 8 + 5] -= s1.y / um;
      r64[c * 8 + 6] -= s1.z / um; r64[c * 8 + 7] -= s1.w / um;
    }
    if (lg == 0) codes_f[(size_t)k * BT + token] = (float)winner;
    // next step's candL write (g==7) is gated by the pre-g-loop barrier.
  }

  // epilogue: write final residual back for proj_out
  {
    float* wrow = rb + (size_t)token * D_ + lg * 8;
#pragma unroll
    for (int c = 0; c < 8; c++) {
      float4 f0 = make_float4(r64[c * 8 + 0], r64[c * 8 + 1],
                              r64[c * 8 + 2], r64[c * 8 + 3]);
      float4 f1 = make_float4(r64[c * 8 + 4], r64[c * 8 + 5],
                              r64[c * 8 + 6], r64[c * 8 + 7]);
      *(float4*)(wrow + c * 32)     = f0;
      *(float4*)(wrow + c * 32 + 4) = f1;
    }
  }
}

// ---------------------------------------------------------------------------
extern "C" void kernel_launch(void* const* d_in, const int* in_sizes, int n_in,
                              void* d_out, int out_size, void* d_ws, size_t ws_size,
                              hipStream_t stream) {
  const float* emb       = (const float*)d_in[0];
  const float* w_in      = (const float*)d_in[1];
  const float* w_out     = (const float*)d_in[2];
  const float* embed_sum = (const float*)d_in[3];
  const float* usage     = (const float*)d_in[4];

  float* outp    = (float*)d_out;
  float* codes_f = outp;
  float* proj_o  = outp + (size_t)K_ * BT;

  float* rb   = (float*)d_ws;                          // BT*D f32 (33.55 MB)
  float* inv  = rb + (size_t)BT * D_;                  // K*N
  float* nrm  = inv + (size_t)K_ * N_;                 // K*N
  int*   cand = (int*)(nrm + (size_t)K_ * N_);         // (unused gap, kept)
  _Float16* ehs = (_Float16*)(cand + (size_t)BT * 6);  // K*N*D f16 (8.39 MB)
  v8h* afragX = (v8h*)(ehs + (size_t)K_ * N_ * D_);    // 512 KB
  float* wc   = (float*)(afragX + 16 * 16 * 64 * 2);   // 1 MB
  v8h* afragO = (v8h*)(wc + 512 * 512);                // 1.5 MB

  hipLaunchKernelGGL(wprep_x_kernel, dim3(256), dim3(64), 0, stream, w_in, afragX);
  hipLaunchKernelGGL(wc_kernel, dim3(1024), dim3(256), 0, stream, w_out, w_in, wc);
  hipLaunchKernelGGL(wprep_o_kernel, dim3(768), dim3(64), 0, stream, wc, w_out, afragO);
  hipLaunchKernelGGL(prep_kernel, dim3(K_ * N_ / 4), dim3(256), 0, stream,
                     embed_sum, usage, inv, nrm, ehs);
  hipLaunchKernelGGL(proj_x_kernel, dim3(BT / 32), dim3(256), 0, stream,
                     emb, afragX, rb);
  hipLaunchKernelGGL(rvq_mega_kernel, dim3(BT / 128), dim3(512), 0, stream,
                     ehs, nrm, inv, usage, embed_sum, rb, codes_f);
  hipLaunchKernelGGL(proj_out_kernel, dim3(BT / 32), dim3(256), 0, stream,
                     emb, rb, afragO, proj_o);
}

// Round 18
// 848.007 us; speedup vs baseline: 1.8758x; 1.0365x over previous
//
#include <hip/hip_runtime.h>
#include <float.h>
#include <math.h>

#define EPSF 1e-5f
#define NRM_BIAS 2048.0f

constexpr int B_  = 8;
constexpr int CIN = 512;
constexpr int T_  = 4096;
constexpr int K_  = 8;
constexpr int N_  = 2048;
constexpr int D_  = 256;
constexpr int BT  = B_ * T_;          // 32768 tokens

typedef _Float16 v8h __attribute__((ext_vector_type(8)));
typedef _Float16 v4h __attribute__((ext_vector_type(4)));
typedef float    v4f __attribute__((ext_vector_type(4)));

static __device__ __forceinline__ unsigned umn(unsigned a, unsigned b) { return a < b ? a : b; }
static __device__ __forceinline__ unsigned umx(unsigned a, unsigned b) { return a > b ? a : b; }

// ---------------------------------------------------------------------------
// prep: inv = 1/clamp(u), nrm = sum_d e^2 + NRM_BIAS; f16 codebook in
// MFMA-fragment-swizzled order (proven, unchanged).
// ---------------------------------------------------------------------------
__global__ void __launch_bounds__(256) prep_kernel(const float* __restrict__ embed_sum,
                                                   const float* __restrict__ usage,
                                                   float* __restrict__ inv,
                                                   float* __restrict__ nrm,
                                                   _Float16* __restrict__ ehs) {
  int w    = threadIdx.x >> 6;
  int lane = threadIdx.x & 63;
  int kn   = blockIdx.x * 4 + w;
  int k    = kn >> 11, n = kn & (N_ - 1);
  const float* s = embed_sum + (size_t)kn * D_;
  float um = fmaxf(usage[kn], EPSF);
  float4 sv = *(const float4*)(s + lane * 4);
  float e0 = sv.x / um, e1 = sv.y / um, e2 = sv.z / um, e3 = sv.w / um;
  float v = e0 * e0 + e1 * e1 + e2 * e2 + e3 * e3;

  int half = n >> 10, chunk = (n >> 4) & 63, r = n & 15;
  int cg = lane >> 1, sub = lane & 1;
  v4h h4; h4[0] = (_Float16)e0; h4[1] = (_Float16)e1;
  h4[2] = (_Float16)e2; h4[3] = (_Float16)e3;
  size_t off16 = ((size_t)((k * 2 + half) * 64 + chunk)) * 4096
               + (size_t)(cg * 16 + r) * 8 + (size_t)sub * 4;
  *(v4h*)(ehs + off16) = h4;

  for (int off = 32; off > 0; off >>= 1) v += __shfl_down(v, off);
  if (lane == 0) { inv[kn] = 1.0f / um; nrm[kn] = v + NRM_BIAS; }
}

// ---------------------------------------------------------------------------
// wprep_x / wc / wprep_o (proven, unchanged)
// ---------------------------------------------------------------------------
__global__ void __launch_bounds__(64) wprep_x_kernel(const float* __restrict__ w_in,
                                                     v8h* __restrict__ afragX) {
  int lane = threadIdx.x;
  int mt = blockIdx.x >> 4, kstep = blockIdx.x & 15;
  int m = mt * 16 + (lane & 15), k0 = kstep * 32 + (lane >> 4) * 8;
  const float* src = w_in + (size_t)m * CIN + k0;
  float4 f0 = *(const float4*)src, f1 = *(const float4*)(src + 4);
  float e[8] = {f0.x, f0.y, f0.z, f0.w, f1.x, f1.y, f1.z, f1.w};
  v8h h, l;
#pragma unroll
  for (int j = 0; j < 8; j++) {
    _Float16 hh = (_Float16)e[j];
    h[j] = hh; l[j] = (_Float16)(e[j] - (float)hh);
  }
  v8h* dst = afragX + ((size_t)blockIdx.x * 64 + lane) * 2;
  dst[0] = h; dst[1] = l;
}

__global__ void __launch_bounds__(256) wc_kernel(const float* __restrict__ w_out,
                                                 const float* __restrict__ w_in,
                                                 float* __restrict__ wc) {
  int c  = blockIdx.x >> 1;
  int cp = (blockIdx.x & 1) * 256 + threadIdx.x;
  float acc = 0.f;
  for (int d = 0; d < D_; d++)
    acc += w_out[(size_t)c * D_ + d] * w_in[(size_t)d * CIN + cp];
  wc[(size_t)c * CIN + cp] = acc;
}

__global__ void __launch_bounds__(64) wprep_o_kernel(const float* __restrict__ wc,
                                                     const float* __restrict__ w_out,
                                                     v8h* __restrict__ afragO) {
  int lane = threadIdx.x;
  int mt = blockIdx.x / 24, kstep = blockIdx.x % 24;
  int m = mt * 16 + (lane & 15), k0 = kstep * 32 + (lane >> 4) * 8;
  float e[8];
  if (k0 < CIN) {
    const float* s = wc + (size_t)m * CIN + k0;
#pragma unroll
    for (int j = 0; j < 8; j++) e[j] = s[j];
  } else {
    const float* s = w_out + (size_t)m * D_ + (k0 - CIN);
#pragma unroll
    for (int j = 0; j < 8; j++) e[j] = -s[j];
  }
  v8h h, l;
#pragma unroll
  for (int j = 0; j < 8; j++) {
    _Float16 hh = (_Float16)e[j];
    h[j] = hh; l[j] = (_Float16)(e[j] - (float)hh);
  }
  v8h* dst = afragO + ((size_t)blockIdx.x * 64 + lane) * 2;
  dst[0] = h; dst[1] = l;
}

// ---------------------------------------------------------------------------
// proj_x: split-3 f16 MFMA, m-split x2 (proven round-6 kernel, unchanged)
// ---------------------------------------------------------------------------
__global__ void __launch_bounds__(256, 4) proj_x_kernel(const float* __restrict__ emb,
                                                        const v8h* __restrict__ afragX,
                                                        float* __restrict__ rb) {
  int tid = threadIdx.x, wave = tid >> 6, lane = tid & 63;
  int lr = lane & 15, lg = lane >> 4;
  int tb = blockIdx.x >> 1, nb = blockIdx.x & 1;
  int t0 = tb * 64 + wave * 16;
  int b  = t0 >> 12;
  const float* ebase = emb + (size_t)b * CIN * T_ + (t0 & (T_ - 1)) + lr;

  v4f acc[8];
#pragma unroll
  for (int nt = 0; nt < 8; nt++) acc[nt] = (v4f){0.f, 0.f, 0.f, 0.f};

  for (int ks = 0; ks < 16; ks++) {
    float e[8];
#pragma unroll
    for (int j = 0; j < 8; j++)
      e[j] = ebase[(size_t)(ks * 32 + lg * 8 + j) * T_];
    v8h Eh, El;
#pragma unroll
    for (int j = 0; j < 8; j++) {
      _Float16 hh = (_Float16)e[j];
      Eh[j] = hh; El[j] = (_Float16)(e[j] - (float)hh);
    }
    const v8h* ap = afragX + ((size_t)ks * 64 + lane) * 2;
#pragma unroll
    for (int nt = 0; nt < 8; nt++) {
      int mt = nb * 8 + nt;
      v8h Wh = ap[(size_t)mt * 2048];
      v8h Wl = ap[(size_t)mt * 2048 + 1];
      acc[nt] = __builtin_amdgcn_mfma_f32_16x16x32_f16(Eh, Wh, acc[nt], 0, 0, 0);
      acc[nt] = __builtin_amdgcn_mfma_f32_16x16x32_f16(El, Wh, acc[nt], 0, 0, 0);
      acc[nt] = __builtin_amdgcn_mfma_f32_16x16x32_f16(Eh, Wl, acc[nt], 0, 0, 0);
    }
  }
#pragma unroll
  for (int nt = 0; nt < 8; nt++)
#pragma unroll
    for (int r = 0; r < 4; r++)
      rb[(size_t)(t0 + lg * 4 + r) * D_ + (nb * 8 + nt) * 16 + lr] = acc[nt][r];
}

// ---------------------------------------------------------------------------
// proj_out (proven round-5 kernel, unchanged)
// ---------------------------------------------------------------------------
__global__ void __launch_bounds__(256, 4) proj_out_kernel(const float* __restrict__ emb,
                                                          const float* __restrict__ rb,
                                                          const v8h* __restrict__ afragO,
                                                          float* __restrict__ outb) {
  int tid = threadIdx.x, wave = tid >> 6, lane = tid & 63;
  int lr = lane & 15, lg = lane >> 4;
  int tb = blockIdx.x >> 1, mb = blockIdx.x & 1;
  int t0 = tb * 64 + wave * 16;
  int b  = t0 >> 12;
  const float* ebase = emb + (size_t)b * CIN * T_ + (t0 & (T_ - 1)) + lr;

  v4f acc[16];
#pragma unroll
  for (int mt = 0; mt < 16; mt++) acc[mt] = (v4f){0.f, 0.f, 0.f, 0.f};

  for (int ks = 0; ks < 24; ks++) {
    float e[8];
    if (ks < 16) {
#pragma unroll
      for (int j = 0; j < 8; j++)
        e[j] = ebase[(size_t)(ks * 32 + lg * 8 + j) * T_];
    } else {
      const float* rrow = rb + (size_t)(t0 + lr) * D_ + (ks - 16) * 32 + lg * 8;
      float4 f0 = *(const float4*)rrow, f1 = *(const float4*)(rrow + 4);
      e[0] = f0.x; e[1] = f0.y; e[2] = f0.z; e[3] = f0.w;
      e[4] = f1.x; e[5] = f1.y; e[6] = f1.z; e[7] = f1.w;
    }
    v8h Bh;
#pragma unroll
    for (int j = 0; j < 8; j++) Bh[j] = (_Float16)e[j];
#pragma unroll
    for (int mt = 0; mt < 16; mt++) {
      v8h Ah = afragO[(((size_t)(mb * 16 + mt) * 24 + ks) * 64 + lane) * 2];
      acc[mt] = __builtin_amdgcn_mfma_f32_16x16x32_f16(Ah, Bh, acc[mt], 0, 0, 0);
    }
  }
  float* op = outb + (size_t)b * CIN * T_ + (t0 & (T_ - 1)) + lr;
#pragma unroll
  for (int mt = 0; mt < 16; mt++)
#pragma unroll
    for (int r = 0; r < 4; r++)
      op[(size_t)((mt + mb * 16) * 16 + lg * 4 + r) * T_] = acc[mt][r];
}

// ---------------------------------------------------------------------------
// merge helper (proven round-6/7 code, unchanged; candL[128][6])
// ---------------------------------------------------------------------------
__device__ __forceinline__ void merge_save(unsigned b1[4], unsigned b2[4], unsigned b3[4],
                                           int half, int wave, int lg, int lr,
                                           int (*candL)[6]) {
#pragma unroll
  for (int rI = 0; rI < 4; rI++) {
    unsigned k1 = b1[rI], k2 = b2[rI], k3 = b3[rI];
    int n1 = (int)(k1 & 127u) * 16 + lr;
    int n2 = (int)(k2 & 127u) * 16 + lr;
    int n3 = (int)(k3 & 127u) * 16 + lr;
    int o0 = 0, o1 = 0, o2v = 0;
#pragma unroll
    for (int round = 0; round < 3; round++) {
      unsigned mk = k1; int mn = n1;
#pragma unroll
      for (int st = 1; st < 16; st <<= 1) {
        unsigned ok = (unsigned)__shfl_xor((int)mk, st);
        int      on = __shfl_xor(mn, st);
        bool t = (ok < mk) || (ok == mk && on < mn);
        mk = t ? ok : mk; mn = t ? on : mn;
      }
      if (round == 0) o0 = mn; else if (round == 1) o1 = mn; else o2v = mn;
      bool own = (k1 == mk) && (n1 == mn);
      k1 = own ? k2 : k1; n1 = own ? n2 : n1;
      k2 = own ? k3 : k2; n2 = own ? n3 : n2;
      k3 = own ? 0xFFFFFFFFu : k3; n3 = own ? 0x7fffffff : n3;
    }
    if (lr == 0) {
      int* cp = candL[wave * 16 + lg * 4 + rI] + half * 3;
      cp[0] = o0; cp[1] = o1; cp[2] = o2v;
    }
  }
}

// ---------------------------------------------------------------------------
// Mega RVQ v11 = round-14 (best: 787 us) + T4 counted-vmcnt, 3-buffer:
//  - 3 x 32 KB staging buffers, depth-2 prefetch: iter g issues group g+2,
//    computes group g, then `s_waitcnt vmcnt(4)` + raw s_barrier — the 4
//    newest loads stay IN FLIGHT across the barrier (only g+1's drain).
//    Removes the per-barrier vmcnt(0) DMA drain (the Sec5 ~20% stall).
//  - last 2 iters peeled with plain __syncthreads (no further issues).
//  - geometry / scan / select / update math byte-identical to r14.
// ---------------------------------------------------------------------------
__global__ void __launch_bounds__(512)
rvq_mega_kernel(const _Float16* __restrict__ ehs,
                const float* __restrict__ nrm,
                const float* __restrict__ inv_,
                const float* __restrict__ usage,
                const float* __restrict__ embed_sum,
                float* __restrict__ rb,
                float* __restrict__ codes_f) {
  __shared__ v8h ldsB[3][2048];   // 96 KB: 3 buf x 4 chunks x 4096 f16
  __shared__ int candL[128][6];

  int tid  = threadIdx.x;
  int wave = tid >> 6, lane = tid & 63;
  int lr = lane & 15, lg = lane >> 4;
  int wbase = blockIdx.x * 128 + wave * 16;
  int token = wbase + lr;

  // prologue: load residual (A-frag layout), once
  float r64[64];
  {
    const float* rrow = rb + (size_t)token * D_ + lg * 8;
#pragma unroll
    for (int c = 0; c < 8; c++) {
      float4 f0 = *(const float4*)(rrow + c * 32);
      float4 f1 = *(const float4*)(rrow + c * 32 + 4);
      r64[c * 8 + 0] = f0.x; r64[c * 8 + 1] = f0.y;
      r64[c * 8 + 2] = f0.z; r64[c * 8 + 3] = f0.w;
      r64[c * 8 + 4] = f1.x; r64[c * 8 + 5] = f1.y;
      r64[c * 8 + 6] = f1.z; r64[c * 8 + 7] = f1.w;
    }
  }

  for (int k = 0; k < K_; k++) {
    // A fragments from register residual (pure VALU)
    v8h A[8];
#pragma unroll
    for (int c = 0; c < 8; c++) {
      v8h a;
#pragma unroll
      for (int j = 0; j < 8; j++) a[j] = (_Float16)r64[c * 8 + j];
      A[c] = a;
    }

    const v8h* src = (const v8h*)(ehs + (size_t)k * 2 * (64 * 4096));
    const float* nrm_k = nrm + (size_t)k * N_;

    unsigned b1[4], b2[4], b3[4];
#pragma unroll
    for (int i = 0; i < 4; i++) { b1[i] = b2[i] = b3[i] = 0xFFFFFFFFu; }

    // stage groups 0 and 1 into buf0/buf1 (4 x 16B per thread each)
#pragma unroll
    for (int q = 0; q < 4; q++) {
      int idx = tid + q * 512;
      __builtin_amdgcn_global_load_lds(
          (__attribute__((address_space(1))) void*)(void*)(src + idx),
          (__attribute__((address_space(3))) void*)(&ldsB[0][idx]), 16, 0, 0);
    }
#pragma unroll
    for (int q = 0; q < 4; q++) {
      int idx = tid + q * 512;
      __builtin_amdgcn_global_load_lds(
          (__attribute__((address_space(1))) void*)(void*)(src + 2048 + idx),
          (__attribute__((address_space(3))) void*)(&ldsB[1][idx]), 16, 0, 0);
    }
    // buf0 ready; buf1's 4 loads may stay in flight
    asm volatile("s_waitcnt vmcnt(4) lgkmcnt(0)" ::: "memory");
    __builtin_amdgcn_sched_barrier(0);
    __builtin_amdgcn_s_barrier();
    __builtin_amdgcn_sched_barrier(0);

    for (int g = 0; g < 30; g++) {
      int cur = g % 3;
      {                                                  // issue group g+2
        const v8h* gsrc = src + (size_t)(g + 2) * 2048;
        v8h* dst = ldsB[(g + 2) % 3];
#pragma unroll
        for (int q = 0; q < 4; q++) {
          int idx = tid + q * 512;
          __builtin_amdgcn_global_load_lds(
              (__attribute__((address_space(1))) void*)(void*)(gsrc + idx),
              (__attribute__((address_space(3))) void*)(&dst[idx]), 16, 0, 0);
        }
      }

      v4f acc[4];
#pragma unroll
      for (int m = 0; m < 4; m++) acc[m] = (v4f){0.f, 0.f, 0.f, 0.f};
#pragma unroll
      for (int c = 0; c < 8; c++) {
#pragma unroll
        for (int m = 0; m < 4; m++) {
          v8h Bf = ldsB[cur][m * 512 + (c * 4 + lg) * 16 + lr];
          acc[m] = __builtin_amdgcn_mfma_f32_16x16x32_f16(A[c], Bf, acc[m], 0, 0, 0);
        }
      }
#pragma unroll
      for (int m = 0; m < 4; m++) {
        unsigned cg = (unsigned)(4 * g + m);
        float nv = nrm_k[cg * 16 + lr];                  // biased +2048 -> s > 0
#pragma unroll
        for (int j = 0; j < 4; j++) {
          float sv = fmaf(-2.0f, acc[m][j], nv);
          unsigned pk = (__float_as_uint(sv) & 0xFFFFFF80u) | cg;
          unsigned t = umx(b1[j], pk);
          unsigned u = umx(b2[j], pk);
          b1[j] = umn(b1[j], pk);
          b2[j] = umn(b2[j], t);
          b3[j] = umn(b3[j], u);
        }
      }
      if (g == 15) {                                     // end of half 0
        merge_save(b1, b2, b3, 0, wave, lg, lr, candL);
#pragma unroll
        for (int i = 0; i < 4; i++) { b1[i] = b2[i] = b3[i] = 0xFFFFFFFFu; }
      }
      // counted drain: group g+1's loads complete; g+2's stay in flight
      asm volatile("s_waitcnt vmcnt(4) lgkmcnt(0)" ::: "memory");
      __builtin_amdgcn_sched_barrier(0);
      __builtin_amdgcn_s_barrier();
      __builtin_amdgcn_sched_barrier(0);
    }

    // tail iters g = 30, 31: no further issues -> full drain barriers
    for (int g = 30; g < 32; g++) {
      int cur = g % 3;
      v4f acc[4];
#pragma unroll
      for (int m = 0; m < 4; m++) acc[m] = (v4f){0.f, 0.f, 0.f, 0.f};
#pragma unroll
      for (int c = 0; c < 8; c++) {
#pragma unroll
        for (int m = 0; m < 4; m++) {
          v8h Bf = ldsB[cur][m * 512 + (c * 4 + lg) * 16 + lr];
          acc[m] = __builtin_amdgcn_mfma_f32_16x16x32_f16(A[c], Bf, acc[m], 0, 0, 0);
        }
      }
#pragma unroll
      for (int m = 0; m < 4; m++) {
        unsigned cg = (unsigned)(4 * g + m);
        float nv = nrm_k[cg * 16 + lr];
#pragma unroll
        for (int j = 0; j < 4; j++) {
          float sv = fmaf(-2.0f, acc[m][j], nv);
          unsigned pk = (__float_as_uint(sv) & 0xFFFFFF80u) | cg;
          unsigned t = umx(b1[j], pk);
          unsigned u = umx(b2[j], pk);
          b1[j] = umn(b1[j], pk);
          b2[j] = umn(b2[j], t);
          b3[j] = umn(b3[j], u);
        }
      }
      __syncthreads();
    }
    merge_save(b1, b2, b3, 1, wave, lg, lr, candL);
    __syncthreads();

    // -------- select: 4 lg-lanes per token (lr), 64 dims each --------
    const float* es_k  = embed_sum + (size_t)k * N_ * D_;
    const float* us_k  = usage + (size_t)k * N_;
    const float* inv_k = inv_  + (size_t)k * N_;

    int c6[6];
#pragma unroll
    for (int i = 0; i < 6; i++) c6[i] = candL[wave * 16 + lr][i];

    float dots[6];
#pragma unroll
    for (int i = 0; i < 6; i++) {
      const float* sr = es_k + (size_t)c6[i] * D_ + lg * 8;
      float a = 0.f;
#pragma unroll
      for (int c = 0; c < 8; c++) {
        float4 s0 = *(const float4*)(sr + c * 32);
        float4 s1 = *(const float4*)(sr + c * 32 + 4);
        a += r64[c * 8 + 0] * s0.x + r64[c * 8 + 1] * s0.y
           + r64[c * 8 + 2] * s0.z + r64[c * 8 + 3] * s0.w
           + r64[c * 8 + 4] * s1.x + r64[c * 8 + 5] * s1.y
           + r64[c * 8 + 6] * s1.z + r64[c * 8 + 7] * s1.w;
      }
      dots[i] = a;
    }
#pragma unroll
    for (int i = 0; i < 6; i++) {
      dots[i] += __shfl_xor(dots[i], 16);
      dots[i] += __shfl_xor(dots[i], 32);
    }

    float bs = FLT_MAX, bv2 = FLT_MAX; int bn = 0x7fffffff, bn2 = 0x7fffffff;
#pragma unroll
    for (int i = 0; i < 6; i++) {
      int n = c6[i];
      float s = nrm_k[n] - 2.0f * inv_k[n] * dots[i];
      bool better = (s < bs) || (s == bs && n < bn);
      bool second = (s < bv2) || (s == bv2 && n < bn2);
      if (better)      { bv2 = bs; bn2 = bn; bs = s; bn = n; }
      else if (second) { bv2 = s;  bn2 = n; }
    }
    int winner = bn;
    if (bv2 - bs < 0.5f && bn2 != bn) {
      double sc[2]; int nn[2] = { bn, bn2 };
#pragma unroll
      for (int cI = 0; cI < 2; cI++) {
        double u = fmax((double)us_k[nn[cI]], 1e-5);
        double uinv = 1.0 / u;
        const float* srow = es_k + (size_t)nn[cI] * D_ + lg * 8;
        double dotre = 0.0, ee = 0.0;
#pragma unroll
        for (int c = 0; c < 8; c++) {
          float4 s0 = *(const float4*)(srow + c * 32);
          float4 s1 = *(const float4*)(srow + c * 32 + 4);
          double e0 = (double)s0.x * uinv, e1 = (double)s0.y * uinv;
          double e2 = (double)s0.z * uinv, e3 = (double)s0.w * uinv;
          double e4 = (double)s1.x * uinv, e5 = (double)s1.y * uinv;
          double e6 = (double)s1.z * uinv, e7 = (double)s1.w * uinv;
          dotre += (double)r64[c * 8 + 0] * e0 + (double)r64[c * 8 + 1] * e1
                 + (double)r64[c * 8 + 2] * e2 + (double)r64[c * 8 + 3] * e3
                 + (double)r64[c * 8 + 4] * e4 + (double)r64[c * 8 + 5] * e5
                 + (double)r64[c * 8 + 6] * e6 + (double)r64[c * 8 + 7] * e7;
          ee += e0 * e0 + e1 * e1 + e2 * e2 + e3 * e3
              + e4 * e4 + e5 * e5 + e6 * e6 + e7 * e7;
        }
        dotre += __shfl_xor(dotre, 16); dotre += __shfl_xor(dotre, 32);
        ee    += __shfl_xor(ee, 16);    ee    += __shfl_xor(ee, 32);
        sc[cI] = ee - 2.0 * dotre;
      }
      if (sc[1] < sc[0] || (sc[1] == sc[0] && nn[1] < nn[0])) winner = nn[1];
    }

    // residual update in registers (exact f32 s/um math)
    float um = fmaxf(us_k[winner], EPSF);
    const float* sw = es_k + (size_t)winner * D_ + lg * 8;
#pragma unroll
    for (int c = 0; c < 8; c++) {
      float4 s0 = *(const float4*)(sw + c * 32);
      float4 s1 = *(const float4*)(sw + c * 32 + 4);
      r64[c * 8 + 0] -= s0.x / um; r64[c * 8 + 1] -= s0.y / um;
      r64[c * 8 + 2] -= s0.z / um; r64[c * 8 + 3] -= s0.w / um;
      r64[c * 8 + 4] -= s1.x / um; r64[c * 8 + 5] -= s1.y / um;
      r64[c * 8 + 6] -= s1.z / um; r64[c * 8 + 7] -= s1.w / um;
    }
    if (lg == 0) codes_f[(size_t)k * BT + token] = (float)winner;
    // next step's candL write (g==15) is gated by the pre-g-loop barrier.
  }

  // epilogue: write final residual back for proj_out
  {
    float* wrow = rb + (size_t)token * D_ + lg * 8;
#pragma unroll
    for (int c = 0; c < 8; c++) {
      float4 f0 = make_float4(r64[c * 8 + 0], r64[c * 8 + 1],
                              r64[c * 8 + 2], r64[c * 8 + 3]);
      float4 f1 = make_float4(r64[c * 8 + 4], r64[c * 8 + 5],
                              r64[c * 8 + 6], r64[c * 8 + 7]);
      *(float4*)(wrow + c * 32)     = f0;
      *(float4*)(wrow + c * 32 + 4) = f1;
    }
  }
}

// ---------------------------------------------------------------------------
extern "C" void kernel_launch(void* const* d_in, const int* in_sizes, int n_in,
                              void* d_out, int out_size, void* d_ws, size_t ws_size,
                              hipStream_t stream) {
  const float* emb       = (const float*)d_in[0];
  const float* w_in      = (const float*)d_in[1];
  const float* w_out     = (const float*)d_in[2];
  const float* embed_sum = (const float*)d_in[3];
  const float* usage     = (const float*)d_in[4];

  float* outp    = (float*)d_out;
  float* codes_f = outp;
  float* proj_o  = outp + (size_t)K_ * BT;

  float* rb   = (float*)d_ws;                          // BT*D f32 (33.55 MB)
  float* inv  = rb + (size_t)BT * D_;                  // K*N
  float* nrm  = inv + (size_t)K_ * N_;                 // K*N
  int*   cand = (int*)(nrm + (size_t)K_ * N_);         // (unused gap, kept)
  _Float16* ehs = (_Float16*)(cand + (size_t)BT * 6);  // K*N*D f16 (8.39 MB)
  v8h* afragX = (v8h*)(ehs + (size_t)K_ * N_ * D_);    // 512 KB
  float* wc   = (float*)(afragX + 16 * 16 * 64 * 2);   // 1 MB
  v8h* afragO = (v8h*)(wc + 512 * 512);                // 1.5 MB

  hipLaunchKernelGGL(wprep_x_kernel, dim3(256), dim3(64), 0, stream, w_in, afragX);
  hipLaunchKernelGGL(wc_kernel, dim3(1024), dim3(256), 0, stream, w_out, w_in, wc);
  hipLaunchKernelGGL(wprep_o_kernel, dim3(768), dim3(64), 0, stream, wc, w_out, afragO);
  hipLaunchKernelGGL(prep_kernel, dim3(K_ * N_ / 4), dim3(256), 0, stream,
                     embed_sum, usage, inv, nrm, ehs);
  hipLaunchKernelGGL(proj_x_kernel, dim3(BT / 32), dim3(256), 0, stream,
                     emb, afragX, rb);
  hipLaunchKernelGGL(rvq_mega_kernel, dim3(BT / 128), dim3(512), 0, stream,
                     ehs, nrm, inv, usage, embed_sum, rb, codes_f);
  hipLaunchKernelGGL(proj_out_kernel, dim3(BT / 32), dim3(256), 0, stream,
                     emb, rb, afragO, proj_o);
}